// Round 1
// baseline (302.797 us; speedup 1.0000x reference)
//
#include <hip/hip_runtime.h>
#include <math.h>

#define NPTS 200001

typedef _Float16 f16;
typedef f16 f16x2 __attribute__((ext_vector_type(2)));
typedef f16 f16x8 __attribute__((ext_vector_type(8)));
typedef float f32x16 __attribute__((ext_vector_type(16)));

// ---------------------------------------------------------------------------
// prep: blocks 0..3: fp32 trapz partial sums for SILU_C / SIG_C
//       blocks 4.. : bake weights into MFMA B-fragment order (f16)
// (unchanged from previous round — layout documented there)
// ---------------------------------------------------------------------------
__global__ void prep(const float* __restrict__ wss0, const float* __restrict__ wvv0,
                     const float* __restrict__ wss1, const float* __restrict__ wvv1,
                     const float* __restrict__ wsv,  const float* __restrict__ wvs,
                     float* __restrict__ partials,
                     f16* __restrict__ b1, f16* __restrict__ b2)
{
    const int b = blockIdx.x;
    const int t = threadIdx.x;
    if (b < 4) {
        float ls = 0.f, lg = 0.f;
        for (int i = b * 256 + t; i < NPTS; i += 1024) {
            float xv  = -12.0f + 24.0f * ((float)i / 200000.0f);
            float pdf = __expf(-0.5f * xv * xv) * 0.39894228040143267794f;
            float sg  = 1.0f / (1.0f + __expf(-xv));
            float si  = xv * sg;
            float wt  = (i == 0 || i == NPTS - 1) ? 0.5f : 1.0f;
            ls = fmaf(wt * si * si, pdf, ls);
            lg = fmaf(wt * sg * sg, pdf, lg);
        }
        __shared__ float r1[256], r2[256];
        r1[t] = ls; r2[t] = lg;
        __syncthreads();
        for (int st = 128; st > 0; st >>= 1) {
            if (t < st) { r1[t] += r1[t + st]; r2[t] += r2[t + st]; }
            __syncthreads();
        }
        if (t == 0) { partials[b] = r1[0]; partials[4 + b] = r2[0]; }
    } else {
        const int gid = (b - 4) * 256 + t;
        const float CSC  = 0.05590169943749474241f;                       // 1/sqrt(320)
        const float CSC3 = 0.05590169943749474241f / 1.7320508075688772935f;
        if (gid < 14336) {                      // B1: [28][64][8]
            const int e = gid;
            const int tt   = e >> 9;
            const int lane = (e >> 3) & 63;
            const int j    = e & 7;
            const int n    = lane & 31;
            const int hf   = lane >> 5;
            const int k    = tt * 16 + hf * 8 + j;
            float val = 0.f;
            if (k < 256) {
                const int u = k >> 4, t16 = k & 15;
                if (n < 16)      val = CSC * wss0[(u * 16 + t16) * 16 + n];
                else if (n < 24) val = CSC * wss1[(u * 16 + t16) * 8 + (n - 16)];
            } else {
                const int kk = k - 256;
                const int r8 = (kk >> 3) & 7, c8 = kk & 7;
                if (n < 16)      val = CSC3 * wvv0[(r8 * 8 + c8) * 16 + n];
                else if (n < 24) val = CSC3 * wvv1[(r8 * 8 + c8) * 8 + (n - 16)];
            }
            b1[e] = (f16)val;
        } else if (gid < 18432) {               // B2: [8][64][8]
            const int e = gid - 14336;
            const int tt   = e >> 9;
            const int lane = (e >> 3) & 63;
            const int j    = e & 7;
            const int n    = lane & 31;
            const int hf   = lane >> 5;
            const int k    = tt * 16 + hf * 8 + j;
            const int a = k >> 3, bb = k & 7;
            float val = 0.f;
            if (n < 8)
                val = 0.0625f * (wsv[(a * 8 + bb) * 8 + n] + wvs[(bb * 16 + a) * 8 + n]);
            b2[e] = (f16)val;
        }
    }
}

// ---------------------------------------------------------------------------
// Main kernel v2: B-fragments staged in LDS (frees ~144 regs vs persistent
// VGPR copies -> target 3-4 waves/SIMD instead of 2), x-row prefetch into the
// same register buffer (load of chunk k+1 issued right after chunk k's
// conversion, lands under 52 MFMAs of compute), grid 512->1024 blocks so
// 4 blocks/CU can be resident (LDS 36,864 B/block -> 4 blocks/CU fits).
// Math identical to previous round: 52x mfma_f32_32x32x16_f16 per 32-row
// chunk, fp32 accum. C-layout: col = lane&31, row = (reg&3)+8*(reg>>2)+4*hf.
// ---------------------------------------------------------------------------
__global__ __launch_bounds__(256, 3) void seg_main(
    const float* __restrict__ x,
    const f16* __restrict__ b1,       // [28][64][8]
    const f16* __restrict__ b2,       // [8][64][8]
    const float* __restrict__ partials,
    float* __restrict__ out, int n, int nchunks)
{
    const int lane = threadIdx.x & 63;
    const int wid  = threadIdx.x >> 6;
    const int col  = lane & 31;
    const int hf   = lane >> 5;

    // ---- stage all B fragments into LDS: 28,672 + 8,192 = 36,864 B ----
    __shared__ float4 ldsB[2304];
    {
        const float4* b1v4 = (const float4*)b1;   // 1792 float4
        const float4* b2v4 = (const float4*)b2;   // 512 float4
#pragma unroll
        for (int i = 0; i < 7; ++i) ldsB[i * 256 + threadIdx.x] = b1v4[i * 256 + threadIdx.x];
#pragma unroll
        for (int i = 0; i < 2; ++i) ldsB[1792 + i * 256 + threadIdx.x] = b2v4[i * 256 + threadIdx.x];
    }
    __syncthreads();
    // frag t of B1 at f16x8 index t*64+lane (contiguous 1024B per wave ->
    // conflict-free ds_read_b128); B2 frag t at 1792 + t*64 + lane.
    const f16x8* Bf = (const f16x8*)ldsB;

    const float dx = 24.0f / 200000.0f;
    const float silu_c = rsqrtf((partials[0] + partials[1] + partials[2] + partials[3]) * dx);
    const float sig_c  = rsqrtf((partials[4] + partials[5] + partials[6] + partials[7]) * dx);

    const int stride = gridDim.x * 4;
    int chunk = blockIdx.x * 4 + wid;

    // prefetch buffer: raw f32 row, lives across the whole loop body
    float xr[40] __attribute__((aligned(16)));
    if (chunk < nchunks) {
        const int row  = chunk * 32 + col;
        const int lrow = (row < n) ? row : (n - 1);
        const float4* p4 = (const float4*)(x + (size_t)lrow * 40);
#pragma unroll
        for (int q = 0; q < 10; ++q) ((float4*)xr)[q] = p4[q];
    }

    for (; chunk < nchunks; chunk += stride) {
        // ---- convert current row to f16 register vectors ----
        f16x2 s2[8];        // s2[a] = {s[2a], s[2a+1]}
        f16x2 vc[3][4];     // vc[i][m] = {v[2m][i], v[2m+1][i]}
#pragma unroll
        for (int a = 0; a < 8; ++a) { s2[a].x = (f16)xr[2 * a]; s2[a].y = (f16)xr[2 * a + 1]; }
#pragma unroll
        for (int i = 0; i < 3; ++i)
#pragma unroll
            for (int m = 0; m < 4; ++m) {
                vc[i][m].x = (f16)xr[16 + 6 * m + i];
                vc[i][m].y = (f16)xr[16 + 6 * m + 3 + i];
            }

        // ---- prefetch next chunk's row into xr (lands under the MFMAs) ----
        {
            const int nxt = chunk + stride;
            if (nxt < nchunks) {
                const int row  = nxt * 32 + col;
                const int lrow = (row < n) ? row : (n - 1);
                const float4* p4 = (const float4*)(x + (size_t)lrow * 40);
#pragma unroll
                for (int q = 0; q < 10; ++q) ((float4*)xr)[q] = p4[q];
            }
        }

        // lane's K-half of s: elements hf*8 .. hf*8+7
        f16x2 shp[4];
#pragma unroll
        for (int m = 0; m < 4; ++m) shp[m] = hf ? s2[4 + m] : s2[m];

        union { f16x2 h[4]; f16x8 v; } A;
        f32x16 acc1;
#pragma unroll
        for (int r = 0; r < 16; ++r) acc1[r] = 0.f;

        // ---- path1 ss: ksteps t=0..15, feature_j = s[t] * s[hf*8+j] ----
#pragma unroll
        for (int t = 0; t < 16; ++t) {
            f16 sv = (t & 1) ? s2[t >> 1].y : s2[t >> 1].x;   // compile-time select
            f16x2 su2; su2.x = sv; su2.y = sv;
#pragma unroll
            for (int m = 0; m < 4; ++m) A.h[m] = su2 * shp[m];
            acc1 = __builtin_amdgcn_mfma_f32_32x32x16_f16(A.v, Bf[t * 64 + lane], acc1, 0, 0, 0);
        }
        // ---- path1 vv: ksteps tt=0..11; i = tt>>2, u = 2*(tt&3)+hf ----
#pragma unroll
        for (int tt = 0; tt < 12; ++tt) {
            const int i   = tt >> 2;
            const int ttm = tt & 3;
            f16x2 pr = vc[i][ttm];
            f16 sv = hf ? pr.y : pr.x;
            f16x2 su2; su2.x = sv; su2.y = sv;
#pragma unroll
            for (int m = 0; m < 4; ++m) A.h[m] = su2 * vc[i][m];
            acc1 = __builtin_amdgcn_mfma_f32_32x32x16_f16(A.v, Bf[(16 + tt) * 64 + lane], acc1, 0, 0, 0);
        }

        // ---- epilogue path1: silu on cols 0..15, gates on cols 16..23 ----
        float gall[16];
#pragma unroll
        for (int r = 0; r < 16; ++r) {
            float val = acc1[r];
            float sgm = 1.0f / (1.0f + __expf(-val));
            gall[r] = sig_c * sgm;
            const int z  = (r & 3) + 8 * (r >> 2) + 4 * hf;
            const int zr = chunk * 32 + z;
            if (col < 16 && zr < n)
                out[(size_t)zr * 40 + col] = silu_c * val * sgm;
        }
        // gate(z, w) lives at col 16+w; for the consuming lanes (col<8, i.e.
        // lane in {0..7, 32..39}) lane+16 == lane^16 -> xor-swizzle, no addr VALU
        float gm[16];
#pragma unroll
        for (int r = 0; r < 16; ++r)
            gm[r] = __int_as_float(__builtin_amdgcn_ds_swizzle(__float_as_int(gall[r]), 0x401F));

        // ---- path2: per component i, M-row = z, N-col = w (0..7) ----
#pragma unroll
        for (int i = 0; i < 3; ++i) {
            f32x16 acc2;
#pragma unroll
            for (int r = 0; r < 16; ++r) acc2[r] = 0.f;
#pragma unroll
            for (int t2 = 0; t2 < 8; ++t2) {        // a = 2*t2 + hf
                f16x2 pr = s2[t2];
                f16 sv = hf ? pr.y : pr.x;
                f16x2 su2; su2.x = sv; su2.y = sv;
#pragma unroll
                for (int m = 0; m < 4; ++m) A.h[m] = su2 * vc[i][m];
                acc2 = __builtin_amdgcn_mfma_f32_32x32x16_f16(A.v, Bf[1792 + t2 * 64 + lane], acc2, 0, 0, 0);
            }
            if (col < 8) {
#pragma unroll
                for (int r = 0; r < 16; ++r) {
                    const int z  = (r & 3) + 8 * (r >> 2) + 4 * hf;
                    const int zr = chunk * 32 + z;
                    if (zr < n)
                        out[(size_t)zr * 40 + 16 + col * 3 + i] = gm[r] * acc2[r];
                }
            }
        }
    }
}

// ---------------------------------------------------------------------------
extern "C" void kernel_launch(void* const* d_in, const int* in_sizes, int n_in,
                              void* d_out, int out_size, void* d_ws, size_t ws_size,
                              hipStream_t stream)
{
    (void)n_in; (void)out_size; (void)ws_size;
    const float* x    = (const float*)d_in[0];
    const float* wss0 = (const float*)d_in[1];
    const float* wvv0 = (const float*)d_in[2];
    const float* wss1 = (const float*)d_in[3];
    const float* wvv1 = (const float*)d_in[4];
    const float* wsv  = (const float*)d_in[5];
    const float* wvs  = (const float*)d_in[6];
    float* out = (float*)d_out;
    const int n = in_sizes[0] / 40;
    const int nchunks = (n + 31) / 32;

    char* ws = (char*)d_ws;
    float* partials = (float*)(ws + 0);        // 8 floats
    f16*   b1       = (f16*)(ws + 1024);       // 28*64*8 f16 = 28672 B
    f16*   b2       = (f16*)(ws + 30720);      // 8*64*8 f16  = 8192 B

    int grid = (nchunks + 3) / 4;
    if (grid > 1024) grid = 1024;

    hipLaunchKernelGGL(prep, dim3(76), dim3(256), 0, stream,
                       wss0, wvv0, wss1, wvv1, wsv, wvs, partials, b1, b2);
    hipLaunchKernelGGL(seg_main, dim3(grid), dim3(256), 0, stream,
                       x, b1, b2, partials, out, n, nchunks);
}